// Round 13
// baseline (26.724 us; speedup 1.0000x reference)
//
#include <hip/hip_runtime.h>

#define GXD 96
#define GYD 96
#define GZD 96
#define PTS_PER_B (GXD * GYD * GZD)
// block = 16x8x8 cells, 256 threads (4 waves), 4 z-points per thread
// wave = 8x8x4 cells (x-half via wave bit1, z-half via wave bit0)
#define BXC 16
#define BYC 8
#define BZC 8
#define GXB (GXD / BXC)   // 6
#define GYB (GYD / BYC)   // 12
#define GZB (GZD / BZC)   // 12
#define BLOCKS_PER_B (GXB * GYB * GZB)  // 864
#define MAXN 16
#define RECL 44           // floats per LDS record
#define BIGF 1e10f
#define GLOWER -1.2f
#define GSTEP 0.025f
#define EPS_G 2e-3f   // two-sided cull margin; |sg - g_chain| <= ~1e-4 (20x margin)

// LDS record layout (floats unless noted):
//  0-2  t      3-6  q(normalized)   7-9  w (raw widths, for exact sliver division)
// 10-12 mx,my,mz=(S-1)f
// 13-21 Mg = diag(1/w)*R^T rows
// 22-24 Cg = -Mg*t - 0.5          (sg = Mg*p + Cg ~ reference g)
// 25-27 wideHi   = m + EPS_G
// 28-30 narrowHi = m - EPS_G
// 31-33 world AABB lo   34-36 world AABB hi
// 37 (int) m*sdf_stride  38-40 (int) SX,SY,SZ
// 41-43 pad

// ---------- exact rotate: identical op order to validated rounds ----------
__device__ __forceinline__ void rot_inv(float qx, float qy, float qz, float qw,
                                        float dx, float dy, float dz,
                                        float& rx, float& ry, float& rz)
{
    float ux = -qx, uy = -qy, uz = -qz;
    float uvx = uy * dz - uz * dy;
    float uvy = uz * dx - ux * dz;
    float uvz = ux * dy - uy * dx;
    float t2x = uvx + qw * dx;
    float t2y = uvy + qw * dy;
    float t2z = uvz + qw * dz;
    rx = dx + 2.0f * (uy * t2z - uz * t2y);
    ry = dy + 2.0f * (uz * t2x - ux * t2z);
    rz = dz + 2.0f * (ux * t2y - uy * t2x);
}

struct __attribute__((aligned(4))) F2 { float lo, hi; };

// trilerp taking g directly (validated rounds 6-11: paired-z gather, exact clamp)
__device__ __forceinline__ float trilerp_g(const float* __restrict__ sd,
                                           float gx, float gy, float gz,
                                           float mx, float my, float mz,
                                           int SX, int SY, int SZ)
{
    float fx = fminf(fmaxf(gx, 0.0f), mx);
    float fy = fminf(fmaxf(gy, 0.0f), my);
    float fz = fminf(fmaxf(gz, 0.0f), mz);
    int i0x = (int)fx, i0y = (int)fy, i0z = (int)fz;  // f>=0 -> trunc==floor
    float frx = fx - (float)i0x;
    float fry = fy - (float)i0y;
    float frz = fz - (float)i0z;
    int i1x = min(i0x + 1, SX - 1);
    int i1y = min(i0y + 1, SY - 1);

    int zb = min(i0z, max(SZ - 2, 0));
    bool at0 = (i0z == zb);

    int b00 = (i0x * SY + i0y) * SZ + zb;
    int b01 = (i0x * SY + i1y) * SZ + zb;
    int b10 = (i1x * SY + i0y) * SZ + zb;
    int b11 = (i1x * SY + i1y) * SZ + zb;

    F2 p00 = *(const F2*)(sd + b00);
    F2 p01 = *(const F2*)(sd + b01);
    F2 p10 = *(const F2*)(sd + b10);
    F2 p11 = *(const F2*)(sd + b11);

    float v000 = at0 ? p00.lo : p00.hi, v001 = p00.hi;
    float v010 = at0 ? p01.lo : p01.hi, v011 = p01.hi;
    float v100 = at0 ? p10.lo : p10.hi, v101 = p10.hi;
    float v110 = at0 ? p11.lo : p11.hi, v111 = p11.hi;

    float c00 = v000 + frz * (v001 - v000);
    float c01 = v010 + frz * (v011 - v010);
    float c10 = v100 + frz * (v101 - v100);
    float c11 = v110 + frz * (v111 - v110);
    float c0 = c00 + fry * (c01 - c00);
    float c1 = c10 + fry * (c11 - c10);
    return c0 + frx * (c1 - c0);
}

// one point: wide/narrow two-sided margin (validated r7-r11); sliver decision is
// the REFERENCE chain verbatim (rot_inv + IEEE division + [0,m] compare) ->
// bit-identical to the round-0 validated kernel by construction.
__device__ __forceinline__ void eval_point(const float* __restrict__ r,
                                           const float* __restrict__ sdfs,
                                           float sgx, float sgy, float sgz,
                                           float px, float py, float pz,
                                           float& best)
{
    bool wide = (sgx >= -EPS_G) & (sgx <= r[25]) &
                (sgy >= -EPS_G) & (sgy <= r[26]) &
                (sgz >= -EPS_G) & (sgz <= r[27]);
    if (!wide) return;

    bool narrow = (sgx >= EPS_G) & (sgx <= r[28]) &
                  (sgy >= EPS_G) & (sgy <= r[29]) &
                  (sgz >= EPS_G) & (sgz <= r[30]);

    float gx = sgx, gy = sgy, gz = sgz;
    bool inside = true;
    if (!narrow) {
        // sliver: exact reference chain -> bit-identical decision
        float dx = px - r[0], dy = py - r[1], dz = pz - r[2];
        float rx, ry, rz;
        rot_inv(r[3], r[4], r[5], r[6], dx, dy, dz, rx, ry, rz);
        gx = rx / r[7] - 0.5f;
        gy = ry / r[8] - 0.5f;
        gz = rz / r[9] - 0.5f;
        inside = (gx >= 0.0f) & (gx <= r[10]) &
                 (gy >= 0.0f) & (gy <= r[11]) &
                 (gz >= 0.0f) & (gz <= r[12]);
    }
    if (inside) {
        const int* ri = (const int*)r;
        float v = trilerp_g(sdfs + ri[37], gx, gy, gz,
                            r[10], r[11], r[12],
                            ri[38], ri[39], ri[40]);
        best = fminf(best, v);
    }
}

__global__ __launch_bounds__(256) void sdf_grid_v12(
    const float* __restrict__ sdfs,
    const int*   __restrict__ shapes,
    const int*   __restrict__ indices,
    const float* __restrict__ poses,
    const float* __restrict__ widths,
    float*       __restrict__ out,
    int N, int sdf_stride)
{
    __shared__ float srec[MAXN][RECL];

    int bidx = blockIdx.x;                 // (xb*GYB + yb)*GZB + zb
    int b = blockIdx.y;
    int zbk = bidx % GZB;
    int ybk = (bidx / GZB) % GYB;
    int xbk = bidx / (GZB * GYB);

    int t = threadIdx.x;

    // ---- in-block prep: thread n (< N) builds record n for batch b ----
    if (t < N) {
        int bn = b * N + t;
        int m = indices[bn];
        const float* pp = poses + (size_t)bn * 7;
        float tx = pp[0], ty = pp[1], tz = pp[2];
        float qx = pp[3], qy = pp[4], qz = pp[5], qw = pp[6];
        // identical op order to validated rounds -> bit-identical q
        float nrm = sqrtf(qx * qx + qy * qy + qz * qz + qw * qw);
        qx = qx / nrm; qy = qy / nrm; qz = qz / nrm; qw = qw / nrm;

        float wx = widths[bn * 3 + 0], wy = widths[bn * 3 + 1], wz = widths[bn * 3 + 2];
        int SX = shapes[m * 3 + 0], SY = shapes[m * 3 + 1], SZ = shapes[m * 3 + 2];
        float mx = (float)(SX - 1), my = (float)(SY - 1), mz = (float)(SZ - 1);

        // rotation matrix R (local->world) from q
        float xx = qx * qx, yy = qy * qy, zz = qz * qz;
        float xy = qx * qy, xz = qx * qz, yz = qy * qz;
        float wqx = qw * qx, wqy = qw * qy, wqz = qw * qz;
        float R00 = 1.0f - 2.0f * (yy + zz), R01 = 2.0f * (xy - wqz), R02 = 2.0f * (xz + wqy);
        float R10 = 2.0f * (xy + wqz), R11 = 1.0f - 2.0f * (xx + zz), R12 = 2.0f * (yz - wqx);
        float R20 = 2.0f * (xz - wqy), R21 = 2.0f * (yz + wqx), R22 = 1.0f - 2.0f * (xx + yy);

        // conservative world AABB (approx extents; MARG >> all rounding) - r10/r11-validated
        float Axa = 0.5f * wx, Aya = 0.5f * wy, Aza = 0.5f * wz;
        float Bxa = (mx + 0.5f) * wx, Bya = (my + 0.5f) * wy, Bza = (mz + 0.5f) * wz;
        float cx = 0.5f * (Axa + Bxa), cy = 0.5f * (Aya + Bya), cz = 0.5f * (Aza + Bza);
        float hx = 0.5f * (Bxa - Axa), hy = 0.5f * (Bya - Aya), hz = 0.5f * (Bza - Aza);
        const float MARG = 2e-3f;
        float wcx = tx + R00 * cx + R01 * cy + R02 * cz;
        float wcy = ty + R10 * cx + R11 * cy + R12 * cz;
        float wcz = tz + R20 * cx + R21 * cy + R22 * cz;
        float ex = fabsf(R00) * hx + fabsf(R01) * hy + fabsf(R02) * hz + MARG;
        float ey = fabsf(R10) * hx + fabsf(R11) * hy + fabsf(R12) * hz + MARG;
        float ez = fabsf(R20) * hx + fabsf(R21) * hy + fabsf(R22) * hz + MARG;

        float iwx = 1.0f / wx, iwy = 1.0f / wy, iwz = 1.0f / wz;
        float Mg0x = iwx * R00, Mg1x = iwx * R10, Mg2x = iwx * R20;
        float Mg0y = iwy * R01, Mg1y = iwy * R11, Mg2y = iwy * R21;
        float Mg0z = iwz * R02, Mg1z = iwz * R12, Mg2z = iwz * R22;
        float Cgx = -0.5f - (Mg0x * tx + Mg1x * ty + Mg2x * tz);
        float Cgy = -0.5f - (Mg0y * tx + Mg1y * ty + Mg2y * tz);
        float Cgz = -0.5f - (Mg0z * tx + Mg1z * ty + Mg2z * tz);

        float* r = srec[t];
        r[0] = tx;  r[1] = ty;  r[2] = tz;
        r[3] = qx;  r[4] = qy;  r[5] = qz;  r[6] = qw;
        r[7] = wx;  r[8] = wy;  r[9] = wz;
        r[10] = mx; r[11] = my; r[12] = mz;
        r[13] = Mg0x; r[14] = Mg1x; r[15] = Mg2x;
        r[16] = Mg0y; r[17] = Mg1y; r[18] = Mg2y;
        r[19] = Mg0z; r[20] = Mg1z; r[21] = Mg2z;
        r[22] = Cgx; r[23] = Cgy; r[24] = Cgz;
        r[25] = mx + EPS_G; r[26] = my + EPS_G; r[27] = mz + EPS_G;
        r[28] = mx - EPS_G; r[29] = my - EPS_G; r[30] = mz - EPS_G;
        r[31] = wcx - ex; r[32] = wcy - ey; r[33] = wcz - ez;
        r[34] = wcx + ex; r[35] = wcy + ey; r[36] = wcz + ez;
        int* ri = (int*)r;
        ri[37] = m * sdf_stride;
        ri[38] = SX; ri[39] = SY; ri[40] = SZ;
    }
    __syncthreads();

    // ---- thread -> 8x8 xy lane; wave bit1 = x-half, bit0 = z-half; 4 z/thread ----
    int lane = t & 63;
    int lyy = lane & 7;
    int lxx = lane >> 3;                   // 0..7
    int wv = t >> 6;                       // 0..3
    int wxh = wv >> 1;                     // x half
    int wzh = wv & 1;                      // z half

    int cx = xbk * BXC + wxh * 8 + lxx;
    int cy = ybk * BYC + lyy;
    int cz0 = zbk * BZC + wzh * 4;         // multiple of 4

    float px  = GLOWER + ((float)cx + 0.5f) * GSTEP;
    float py  = GLOWER + ((float)cy + 0.5f) * GSTEP;
    float pz0 = GLOWER + ((float)cz0 + 0.5f) * GSTEP;
    float pz1 = GLOWER + ((float)(cz0 + 1) + 0.5f) * GSTEP;
    float pz2 = GLOWER + ((float)(cz0 + 2) + 0.5f) * GSTEP;
    float pz3 = GLOWER + ((float)(cz0 + 3) + 0.5f) * GSTEP;

    size_t out_idx = (size_t)b * PTS_PER_B + ((size_t)cx * GYD + cy) * GZD + cz0;

    // ---- per-wave ballot mask vs the wave's own 8x8x4 cube (validated r10/r11) ----
    float bxl = GLOWER + ((float)(xbk * BXC + wxh * 8) + 0.5f) * GSTEP;
    float bxh = GLOWER + ((float)(xbk * BXC + wxh * 8 + 7) + 0.5f) * GSTEP;
    float byl = GLOWER + ((float)(ybk * BYC) + 0.5f) * GSTEP;
    float byh = GLOWER + ((float)(ybk * BYC + 7) + 0.5f) * GSTEP;
    float bzl = GLOWER + ((float)(zbk * BZC + wzh * 4) + 0.5f) * GSTEP;
    float bzh = GLOWER + ((float)(zbk * BZC + wzh * 4 + 3) + 0.5f) * GSTEP;

    bool lok = false;
    if (lane < N) {
        const float* r = srec[lane];
        lok = (bxh >= r[31]) & (bxl <= r[34]) &
              (byh >= r[32]) & (byl <= r[35]) &
              (bzh >= r[33]) & (bzl <= r[36]);
    }
    unsigned int msk = (unsigned int)__ballot(lok);

    if (msk == 0u) {
        *(float4*)(out + out_idx) = make_float4(BIGF, BIGF, BIGF, BIGF);
        return;
    }

    float b0 = BIGF, b1 = BIGF, b2 = BIGF, b3 = BIGF;

    for (int n = 0; n < N; ++n) {
        if (!((msk >> n) & 1u)) continue;  // whole wave certainly outside SDF n

        const float* r = srec[n];

        // affine g at k=0; k=1..3 via increments (drift ~1e-6 << EPS_G;
        // sliver path recomputes the exact reference chain anyway) - r9/r11-validated
        float sgx = fmaf(r[13], px, fmaf(r[14], py, fmaf(r[15], pz0, r[22])));
        float sgy = fmaf(r[16], px, fmaf(r[17], py, fmaf(r[18], pz0, r[23])));
        float sgz = fmaf(r[19], px, fmaf(r[20], py, fmaf(r[21], pz0, r[24])));
        float dgx = GSTEP * r[15];
        float dgy = GSTEP * r[18];
        float dgz = GSTEP * r[21];

        eval_point(r, sdfs, sgx, sgy, sgz, px, py, pz0, b0);
        float s1x = sgx + dgx, s1y = sgy + dgy, s1z = sgz + dgz;
        eval_point(r, sdfs, s1x, s1y, s1z, px, py, pz1, b1);
        float s2x = s1x + dgx, s2y = s1y + dgy, s2z = s1z + dgz;
        eval_point(r, sdfs, s2x, s2y, s2z, px, py, pz2, b2);
        float s3x = s2x + dgx, s3y = s2y + dgy, s3z = s2z + dgz;
        eval_point(r, sdfs, s3x, s3y, s3z, px, py, pz3, b3);
    }

    *(float4*)(out + out_idx) = make_float4(b0, b1, b2, b3);
}

// ---------------- fallback: round-0 validated monolithic kernel ----------------
__global__ __launch_bounds__(256) void sdf_grid_kernel(
    const float* __restrict__ sdfs,
    const int*   __restrict__ sdf_shapes,
    const int*   __restrict__ indices,
    const float* __restrict__ poses,
    const float* __restrict__ widths,
    float*       __restrict__ out,
    int total, int N, int sdf_stride)
{
    int idx = blockIdx.x * blockDim.x + threadIdx.x;
    if (idx >= total) return;
    int z = idx % GZD;
    int y = (idx / GZD) % GYD;
    int x = (idx / (GZD * GYD)) % GXD;
    int b = idx / (GZD * GYD * GXD);
    float px = GLOWER + ((float)x + 0.5f) * GSTEP;
    float py = GLOWER + ((float)y + 0.5f) * GSTEP;
    float pz = GLOWER + ((float)z + 0.5f) * GSTEP;
    float best = BIGF;
    for (int n = 0; n < N; ++n) {
        int bn = b * N + n;
        int m  = indices[bn];
        const float* pp = poses + (size_t)bn * 7;
        float tx = pp[0], ty = pp[1], tz = pp[2];
        float qx = pp[3], qy = pp[4], qz = pp[5], qw = pp[6];
        float nrm = sqrtf(qx * qx + qy * qy + qz * qz + qw * qw);
        qx = qx / nrm; qy = qy / nrm; qz = qz / nrm; qw = qw / nrm;
        float dx = px - tx, dy = py - ty, dz = pz - tz;
        float rx, ry, rz;
        rot_inv(qx, qy, qz, qw, dx, dy, dz, rx, ry, rz);
        const float* ww = widths + (size_t)bn * 3;
        float gx = rx / ww[0] - 0.5f;
        float gy = ry / ww[1] - 0.5f;
        float gz = rz / ww[2] - 0.5f;
        int SX = sdf_shapes[m * 3 + 0];
        int SY = sdf_shapes[m * 3 + 1];
        int SZ = sdf_shapes[m * 3 + 2];
        float mx = (float)(SX - 1), my = (float)(SY - 1), mz = (float)(SZ - 1);
        bool inside = (gx >= 0.0f) && (gx <= mx) &&
                      (gy >= 0.0f) && (gy <= my) &&
                      (gz >= 0.0f) && (gz <= mz);
        float fx = fminf(fmaxf(gx, 0.0f), mx);
        float fy = fminf(fmaxf(gy, 0.0f), my);
        float fz = fminf(fmaxf(gz, 0.0f), mz);
        int i0x = (int)floorf(fx), i0y = (int)floorf(fy), i0z = (int)floorf(fz);
        float frx = fx - (float)i0x, fry = fy - (float)i0y, frz = fz - (float)i0z;
        int i1x = min(i0x + 1, SX - 1);
        int i1y = min(i0y + 1, SY - 1);
        int i1z = min(i0z + 1, SZ - 1);
        const float* sd = sdfs + (size_t)m * sdf_stride;
        int b00 = (i0x * SY + i0y) * SZ;
        int b01 = (i0x * SY + i1y) * SZ;
        int b10 = (i1x * SY + i0y) * SZ;
        int b11 = (i1x * SY + i1y) * SZ;
        float v000 = sd[b00 + i0z], v001 = sd[b00 + i1z];
        float v010 = sd[b01 + i0z], v011 = sd[b01 + i1z];
        float v100 = sd[b10 + i0z], v101 = sd[b10 + i1z];
        float v110 = sd[b11 + i0z], v111 = sd[b11 + i1z];
        float wx0 = 1.0f - frx, wx1 = frx;
        float wy0 = 1.0f - fry, wy1 = fry;
        float wz0 = 1.0f - frz, wz1 = frz;
        float acc = wx0 * wy0 * wz0 * v000 + wx0 * wy0 * wz1 * v001
                  + wx0 * wy1 * wz0 * v010 + wx0 * wy1 * wz1 * v011
                  + wx1 * wy0 * wz0 * v100 + wx1 * wy0 * wz1 * v101
                  + wx1 * wy1 * wz0 * v110 + wx1 * wy1 * wz1 * v111;
        float val = inside ? acc : BIGF;
        best = fminf(best, val);
    }
    out[idx] = best;
}

extern "C" void kernel_launch(void* const* d_in, const int* in_sizes, int n_in,
                              void* d_out, int out_size, void* d_ws, size_t ws_size,
                              hipStream_t stream) {
    const float* sdfs    = (const float*)d_in[0];
    const int*   shapes  = (const int*)d_in[1];
    const int*   indices = (const int*)d_in[2];
    const float* poses   = (const float*)d_in[3];
    const float* widths  = (const float*)d_in[4];
    float*       out     = (float*)d_out;

    int M = in_sizes[1] / 3;           // sdf_shapes is (M,3)
    int sdf_stride = in_sizes[0] / M;  // elements per SDF volume
    int B = out_size / PTS_PER_B;
    int N = in_sizes[2] / B;           // indices is (B,N)

    if (N <= MAXN && (PTS_PER_B % 1024) == 0) {
        dim3 grid(BLOCKS_PER_B, B);
        sdf_grid_v12<<<grid, 256, 0, stream>>>(
            sdfs, shapes, indices, poses, widths, out, N, sdf_stride);
    } else {
        int total = out_size;
        int blocks = (total + 255) / 256;
        sdf_grid_kernel<<<blocks, 256, 0, stream>>>(
            sdfs, shapes, indices, poses, widths, out, total, N, sdf_stride);
    }
}

// Round 14
// 24.812 us; speedup vs baseline: 1.0771x; 1.0771x over previous
//
#include <hip/hip_runtime.h>

#define GXD 96
#define GYD 96
#define GZD 96
#define PTS_PER_B (GXD * GYD * GZD)
// block = 8x8x8 cells, 128 threads, 4 z-points per thread; wave = 8x8x4 cells
#define BXC 8
#define BYC 8
#define BZC 8
#define GXB (GXD / BXC)   // 12
#define GYB (GYD / BYC)   // 12
#define GZB (GZD / BZC)   // 12
#define BLOCKS_PER_B (GXB * GYB * GZB)  // 1728
#define MAXN 16
#define RECL 44           // floats per LDS record
#define BIGF 1e10f
#define GLOWER -1.2f
#define GSTEP 0.025f
#define EPS_G 2e-3f   // two-sided cull margin; |sg - g_chain| <= ~1e-4 (20x margin)

// LDS record layout (floats unless noted):
//  0-2  t      3-6  q(normalized)   7-9  w (raw widths, for exact sliver division)
// 10-12 mx,my,mz=(S-1)f
// 13-21 Mg = diag(1/w)*R^T rows
// 22-24 Cg = -Mg*t - 0.5          (sg = Mg*p + Cg ~ reference g)
// 25-27 wideHi   = m + EPS_G
// 28-30 narrowHi = m - EPS_G
// 31-33 world AABB lo   34-36 world AABB hi
// 37 (int) m*sdf_stride  38-40 (int) SX,SY,SZ
// 41-43 pad

// ---------- exact rotate: identical op order to validated rounds ----------
__device__ __forceinline__ void rot_inv(float qx, float qy, float qz, float qw,
                                        float dx, float dy, float dz,
                                        float& rx, float& ry, float& rz)
{
    float ux = -qx, uy = -qy, uz = -qz;
    float uvx = uy * dz - uz * dy;
    float uvy = uz * dx - ux * dz;
    float uvz = ux * dy - uy * dx;
    float t2x = uvx + qw * dx;
    float t2y = uvy + qw * dy;
    float t2z = uvz + qw * dz;
    rx = dx + 2.0f * (uy * t2z - uz * t2y);
    ry = dy + 2.0f * (uz * t2x - ux * t2z);
    rz = dz + 2.0f * (ux * t2y - uy * t2x);
}

struct __attribute__((aligned(4))) F2 { float lo, hi; };

// trilerp taking g directly (validated rounds 6-12: paired-z gather, exact clamp)
__device__ __forceinline__ float trilerp_g(const float* __restrict__ sd,
                                           float gx, float gy, float gz,
                                           float mx, float my, float mz,
                                           int SX, int SY, int SZ)
{
    float fx = fminf(fmaxf(gx, 0.0f), mx);
    float fy = fminf(fmaxf(gy, 0.0f), my);
    float fz = fminf(fmaxf(gz, 0.0f), mz);
    int i0x = (int)fx, i0y = (int)fy, i0z = (int)fz;  // f>=0 -> trunc==floor
    float frx = fx - (float)i0x;
    float fry = fy - (float)i0y;
    float frz = fz - (float)i0z;
    int i1x = min(i0x + 1, SX - 1);
    int i1y = min(i0y + 1, SY - 1);

    int zb = min(i0z, max(SZ - 2, 0));
    bool at0 = (i0z == zb);

    int b00 = (i0x * SY + i0y) * SZ + zb;
    int b01 = (i0x * SY + i1y) * SZ + zb;
    int b10 = (i1x * SY + i0y) * SZ + zb;
    int b11 = (i1x * SY + i1y) * SZ + zb;

    F2 p00 = *(const F2*)(sd + b00);
    F2 p01 = *(const F2*)(sd + b01);
    F2 p10 = *(const F2*)(sd + b10);
    F2 p11 = *(const F2*)(sd + b11);

    float v000 = at0 ? p00.lo : p00.hi, v001 = p00.hi;
    float v010 = at0 ? p01.lo : p01.hi, v011 = p01.hi;
    float v100 = at0 ? p10.lo : p10.hi, v101 = p10.hi;
    float v110 = at0 ? p11.lo : p11.hi, v111 = p11.hi;

    float c00 = v000 + frz * (v001 - v000);
    float c01 = v010 + frz * (v011 - v010);
    float c10 = v100 + frz * (v101 - v100);
    float c11 = v110 + frz * (v111 - v110);
    float c0 = c00 + fry * (c01 - c00);
    float c1 = c10 + fry * (c11 - c10);
    return c0 + frx * (c1 - c0);
}

// one point: wide/narrow two-sided margin (validated r7-r12); sliver decision is
// the REFERENCE chain verbatim (rot_inv + IEEE division + [0,m] compare) ->
// bit-identical to the round-0 validated kernel by construction.
__device__ __forceinline__ void eval_point(const float* __restrict__ r,
                                           const float* __restrict__ sdfs,
                                           float sgx, float sgy, float sgz,
                                           float px, float py, float pz,
                                           float& best)
{
    bool wide = (sgx >= -EPS_G) & (sgx <= r[25]) &
                (sgy >= -EPS_G) & (sgy <= r[26]) &
                (sgz >= -EPS_G) & (sgz <= r[27]);
    if (!wide) return;

    bool narrow = (sgx >= EPS_G) & (sgx <= r[28]) &
                  (sgy >= EPS_G) & (sgy <= r[29]) &
                  (sgz >= EPS_G) & (sgz <= r[30]);

    float gx = sgx, gy = sgy, gz = sgz;
    bool inside = true;
    if (!narrow) {
        // sliver: exact reference chain -> bit-identical decision
        float dx = px - r[0], dy = py - r[1], dz = pz - r[2];
        float rx, ry, rz;
        rot_inv(r[3], r[4], r[5], r[6], dx, dy, dz, rx, ry, rz);
        gx = rx / r[7] - 0.5f;
        gy = ry / r[8] - 0.5f;
        gz = rz / r[9] - 0.5f;
        inside = (gx >= 0.0f) & (gx <= r[10]) &
                 (gy >= 0.0f) & (gy <= r[11]) &
                 (gz >= 0.0f) & (gz <= r[12]);
    }
    if (inside) {
        const int* ri = (const int*)r;
        float v = trilerp_g(sdfs + ri[37], gx, gy, gz,
                            r[10], r[11], r[12],
                            ri[38], ri[39], ri[40]);
        best = fminf(best, v);
    }
}

__global__ __launch_bounds__(128) void sdf_grid_v13(
    const float* __restrict__ sdfs,
    const int*   __restrict__ shapes,
    const int*   __restrict__ indices,
    const float* __restrict__ poses,
    const float* __restrict__ widths,
    float*       __restrict__ out,
    int N, int sdf_stride)
{
    __shared__ float srec[MAXN][RECL];

    int bidx = blockIdx.x;                 // (xb*GYB + yb)*GZB + zb
    int b = blockIdx.y;
    int zbk = bidx % GZB;
    int ybk = (bidx / GZB) % GYB;
    int xbk = bidx / (GZB * GYB);

    int t = threadIdx.x;

    // ---- in-block prep: thread n (< N) builds record n for batch b ----
    if (t < N) {
        int bn = b * N + t;
        int m = indices[bn];
        const float* pp = poses + (size_t)bn * 7;
        float tx = pp[0], ty = pp[1], tz = pp[2];
        float qx = pp[3], qy = pp[4], qz = pp[5], qw = pp[6];
        // identical op order to validated rounds -> bit-identical q
        float nrm = sqrtf(qx * qx + qy * qy + qz * qz + qw * qw);
        qx = qx / nrm; qy = qy / nrm; qz = qz / nrm; qw = qw / nrm;

        float wx = widths[bn * 3 + 0], wy = widths[bn * 3 + 1], wz = widths[bn * 3 + 2];
        int SX = shapes[m * 3 + 0], SY = shapes[m * 3 + 1], SZ = shapes[m * 3 + 2];
        float mx = (float)(SX - 1), my = (float)(SY - 1), mz = (float)(SZ - 1);

        // rotation matrix R (local->world) from q
        float xx = qx * qx, yy = qy * qy, zz = qz * qz;
        float xy = qx * qy, xz = qx * qz, yz = qy * qz;
        float wqx = qw * qx, wqy = qw * qy, wqz = qw * qz;
        float R00 = 1.0f - 2.0f * (yy + zz), R01 = 2.0f * (xy - wqz), R02 = 2.0f * (xz + wqy);
        float R10 = 2.0f * (xy + wqz), R11 = 1.0f - 2.0f * (xx + zz), R12 = 2.0f * (yz - wqx);
        float R20 = 2.0f * (xz - wqy), R21 = 2.0f * (yz + wqx), R22 = 1.0f - 2.0f * (xx + yy);

        // conservative world AABB (approx extents; MARG >> all rounding) - r10/r11-validated
        float Axa = 0.5f * wx, Aya = 0.5f * wy, Aza = 0.5f * wz;
        float Bxa = (mx + 0.5f) * wx, Bya = (my + 0.5f) * wy, Bza = (mz + 0.5f) * wz;
        float cx = 0.5f * (Axa + Bxa), cy = 0.5f * (Aya + Bya), cz = 0.5f * (Aza + Bza);
        float hx = 0.5f * (Bxa - Axa), hy = 0.5f * (Bya - Aya), hz = 0.5f * (Bza - Aza);
        const float MARG = 2e-3f;
        float wcx = tx + R00 * cx + R01 * cy + R02 * cz;
        float wcy = ty + R10 * cx + R11 * cy + R12 * cz;
        float wcz = tz + R20 * cx + R21 * cy + R22 * cz;
        float ex = fabsf(R00) * hx + fabsf(R01) * hy + fabsf(R02) * hz + MARG;
        float ey = fabsf(R10) * hx + fabsf(R11) * hy + fabsf(R12) * hz + MARG;
        float ez = fabsf(R20) * hx + fabsf(R21) * hy + fabsf(R22) * hz + MARG;

        float iwx = 1.0f / wx, iwy = 1.0f / wy, iwz = 1.0f / wz;
        float Mg0x = iwx * R00, Mg1x = iwx * R10, Mg2x = iwx * R20;
        float Mg0y = iwy * R01, Mg1y = iwy * R11, Mg2y = iwy * R21;
        float Mg0z = iwz * R02, Mg1z = iwz * R12, Mg2z = iwz * R22;
        float Cgx = -0.5f - (Mg0x * tx + Mg1x * ty + Mg2x * tz);
        float Cgy = -0.5f - (Mg0y * tx + Mg1y * ty + Mg2y * tz);
        float Cgz = -0.5f - (Mg0z * tx + Mg1z * ty + Mg2z * tz);

        float* r = srec[t];
        r[0] = tx;  r[1] = ty;  r[2] = tz;
        r[3] = qx;  r[4] = qy;  r[5] = qz;  r[6] = qw;
        r[7] = wx;  r[8] = wy;  r[9] = wz;
        r[10] = mx; r[11] = my; r[12] = mz;
        r[13] = Mg0x; r[14] = Mg1x; r[15] = Mg2x;
        r[16] = Mg0y; r[17] = Mg1y; r[18] = Mg2y;
        r[19] = Mg0z; r[20] = Mg1z; r[21] = Mg2z;
        r[22] = Cgx; r[23] = Cgy; r[24] = Cgz;
        r[25] = mx + EPS_G; r[26] = my + EPS_G; r[27] = mz + EPS_G;
        r[28] = mx - EPS_G; r[29] = my - EPS_G; r[30] = mz - EPS_G;
        r[31] = wcx - ex; r[32] = wcy - ey; r[33] = wcz - ez;
        r[34] = wcx + ex; r[35] = wcy + ey; r[36] = wcz + ez;
        int* ri = (int*)r;
        ri[37] = m * sdf_stride;
        ri[38] = SX; ri[39] = SY; ri[40] = SZ;
    }
    __syncthreads();

    // ---- thread -> 8x8 xy lane, wave owns z-half; thread owns 4 z-points ----
    int lane = t & 63;
    int lyy = lane & 7;
    int lxx = lane >> 3;                   // 0..7
    int wz4 = (t >> 6) & 1;                // wave z half: 0 or 1

    int cx = xbk * BXC + lxx;
    int cy = ybk * BYC + lyy;
    int cz0 = zbk * BZC + wz4 * 4;         // multiple of 4

    float px  = GLOWER + ((float)cx + 0.5f) * GSTEP;
    float py  = GLOWER + ((float)cy + 0.5f) * GSTEP;
    float pz0 = GLOWER + ((float)cz0 + 0.5f) * GSTEP;
    float pz1 = GLOWER + ((float)(cz0 + 1) + 0.5f) * GSTEP;
    float pz2 = GLOWER + ((float)(cz0 + 2) + 0.5f) * GSTEP;
    float pz3 = GLOWER + ((float)(cz0 + 3) + 0.5f) * GSTEP;

    size_t out_idx = (size_t)b * PTS_PER_B + ((size_t)cx * GYD + cy) * GZD + cz0;

    // ---- per-wave ballot mask vs the wave's own 8x8x4 cube ----
    float bxl = GLOWER + ((float)(xbk * BXC) + 0.5f) * GSTEP;
    float bxh = GLOWER + ((float)(xbk * BXC + 7) + 0.5f) * GSTEP;
    float byl = GLOWER + ((float)(ybk * BYC) + 0.5f) * GSTEP;
    float byh = GLOWER + ((float)(ybk * BYC + 7) + 0.5f) * GSTEP;
    float bzl = GLOWER + ((float)(zbk * BZC + wz4 * 4) + 0.5f) * GSTEP;
    float bzh = GLOWER + ((float)(zbk * BZC + wz4 * 4 + 3) + 0.5f) * GSTEP;

    bool lok = false;
    if (lane < N) {
        const float* r = srec[lane];
        lok = (bxh >= r[31]) & (bxl <= r[34]) &
              (byh >= r[32]) & (byl <= r[35]) &
              (bzh >= r[33]) & (bzl <= r[36]);
    }
    unsigned int msk = (unsigned int)__ballot(lok);

    if (msk == 0u) {
        *(float4*)(out + out_idx) = make_float4(BIGF, BIGF, BIGF, BIGF);
        return;
    }

    float b0 = BIGF, b1 = BIGF, b2 = BIGF, b3 = BIGF;

    for (int n = 0; n < N; ++n) {
        if (!((msk >> n) & 1u)) continue;  // whole wave certainly outside SDF n

        const float* r = srec[n];

        // affine g at k=0; k=1..3 via increments (drift ~1e-6 << EPS_G;
        // sliver path recomputes the exact reference chain anyway) - r9/r11-validated
        float sgx = fmaf(r[13], px, fmaf(r[14], py, fmaf(r[15], pz0, r[22])));
        float sgy = fmaf(r[16], px, fmaf(r[17], py, fmaf(r[18], pz0, r[23])));
        float sgz = fmaf(r[19], px, fmaf(r[20], py, fmaf(r[21], pz0, r[24])));
        float dgx = GSTEP * r[15];
        float dgy = GSTEP * r[18];
        float dgz = GSTEP * r[21];

        eval_point(r, sdfs, sgx, sgy, sgz, px, py, pz0, b0);
        float s1x = sgx + dgx, s1y = sgy + dgy, s1z = sgz + dgz;
        eval_point(r, sdfs, s1x, s1y, s1z, px, py, pz1, b1);
        float s2x = s1x + dgx, s2y = s1y + dgy, s2z = s1z + dgz;
        eval_point(r, sdfs, s2x, s2y, s2z, px, py, pz2, b2);
        float s3x = s2x + dgx, s3y = s2y + dgy, s3z = s2z + dgz;
        eval_point(r, sdfs, s3x, s3y, s3z, px, py, pz3, b3);
    }

    *(float4*)(out + out_idx) = make_float4(b0, b1, b2, b3);
}

// ---------------- fallback: round-0 validated monolithic kernel ----------------
__global__ __launch_bounds__(256) void sdf_grid_kernel(
    const float* __restrict__ sdfs,
    const int*   __restrict__ sdf_shapes,
    const int*   __restrict__ indices,
    const float* __restrict__ poses,
    const float* __restrict__ widths,
    float*       __restrict__ out,
    int total, int N, int sdf_stride)
{
    int idx = blockIdx.x * blockDim.x + threadIdx.x;
    if (idx >= total) return;
    int z = idx % GZD;
    int y = (idx / GZD) % GYD;
    int x = (idx / (GZD * GYD)) % GXD;
    int b = idx / (GZD * GYD * GXD);
    float px = GLOWER + ((float)x + 0.5f) * GSTEP;
    float py = GLOWER + ((float)y + 0.5f) * GSTEP;
    float pz = GLOWER + ((float)z + 0.5f) * GSTEP;
    float best = BIGF;
    for (int n = 0; n < N; ++n) {
        int bn = b * N + n;
        int m  = indices[bn];
        const float* pp = poses + (size_t)bn * 7;
        float tx = pp[0], ty = pp[1], tz = pp[2];
        float qx = pp[3], qy = pp[4], qz = pp[5], qw = pp[6];
        float nrm = sqrtf(qx * qx + qy * qy + qz * qz + qw * qw);
        qx = qx / nrm; qy = qy / nrm; qz = qz / nrm; qw = qw / nrm;
        float dx = px - tx, dy = py - ty, dz = pz - tz;
        float rx, ry, rz;
        rot_inv(qx, qy, qz, qw, dx, dy, dz, rx, ry, rz);
        const float* ww = widths + (size_t)bn * 3;
        float gx = rx / ww[0] - 0.5f;
        float gy = ry / ww[1] - 0.5f;
        float gz = rz / ww[2] - 0.5f;
        int SX = sdf_shapes[m * 3 + 0];
        int SY = sdf_shapes[m * 3 + 1];
        int SZ = sdf_shapes[m * 3 + 2];
        float mx = (float)(SX - 1), my = (float)(SY - 1), mz = (float)(SZ - 1);
        bool inside = (gx >= 0.0f) && (gx <= mx) &&
                      (gy >= 0.0f) && (gy <= my) &&
                      (gz >= 0.0f) && (gz <= mz);
        float fx = fminf(fmaxf(gx, 0.0f), mx);
        float fy = fminf(fmaxf(gy, 0.0f), my);
        float fz = fminf(fmaxf(gz, 0.0f), mz);
        int i0x = (int)floorf(fx), i0y = (int)floorf(fy), i0z = (int)floorf(fz);
        float frx = fx - (float)i0x, fry = fy - (float)i0y, frz = fz - (float)i0z;
        int i1x = min(i0x + 1, SX - 1);
        int i1y = min(i0y + 1, SY - 1);
        int i1z = min(i0z + 1, SZ - 1);
        const float* sd = sdfs + (size_t)m * sdf_stride;
        int b00 = (i0x * SY + i0y) * SZ;
        int b01 = (i0x * SY + i1y) * SZ;
        int b10 = (i1x * SY + i0y) * SZ;
        int b11 = (i1x * SY + i1y) * SZ;
        float v000 = sd[b00 + i0z], v001 = sd[b00 + i1z];
        float v010 = sd[b01 + i0z], v011 = sd[b01 + i1z];
        float v100 = sd[b10 + i0z], v101 = sd[b10 + i1z];
        float v110 = sd[b11 + i0z], v111 = sd[b11 + i1z];
        float wx0 = 1.0f - frx, wx1 = frx;
        float wy0 = 1.0f - fry, wy1 = fry;
        float wz0 = 1.0f - frz, wz1 = frz;
        float acc = wx0 * wy0 * wz0 * v000 + wx0 * wy0 * wz1 * v001
                  + wx0 * wy1 * wz0 * v010 + wx0 * wy1 * wz1 * v011
                  + wx1 * wy0 * wz0 * v100 + wx1 * wy0 * wz1 * v101
                  + wx1 * wy1 * wz0 * v110 + wx1 * wy1 * wz1 * v111;
        float val = inside ? acc : BIGF;
        best = fminf(best, val);
    }
    out[idx] = best;
}

extern "C" void kernel_launch(void* const* d_in, const int* in_sizes, int n_in,
                              void* d_out, int out_size, void* d_ws, size_t ws_size,
                              hipStream_t stream) {
    const float* sdfs    = (const float*)d_in[0];
    const int*   shapes  = (const int*)d_in[1];
    const int*   indices = (const int*)d_in[2];
    const float* poses   = (const float*)d_in[3];
    const float* widths  = (const float*)d_in[4];
    float*       out     = (float*)d_out;

    int M = in_sizes[1] / 3;           // sdf_shapes is (M,3)
    int sdf_stride = in_sizes[0] / M;  // elements per SDF volume
    int B = out_size / PTS_PER_B;
    int N = in_sizes[2] / B;           // indices is (B,N)

    if (N <= MAXN && (PTS_PER_B % 512) == 0) {
        dim3 grid(BLOCKS_PER_B, B);
        sdf_grid_v13<<<grid, 128, 0, stream>>>(
            sdfs, shapes, indices, poses, widths, out, N, sdf_stride);
    } else {
        int total = out_size;
        int blocks = (total + 255) / 256;
        sdf_grid_kernel<<<blocks, 256, 0, stream>>>(
            sdfs, shapes, indices, poses, widths, out, total, N, sdf_stride);
    }
}